// Round 7
// baseline (886.612 us; speedup 1.0000x reference)
//
#include <hip/hip_runtime.h>

#define IN_F 48
#define EDGE_F 32
#define HID_F 128
#define OUT_F 64

// pack layout: e in bits [0,21), s in [21,42), d in [42,63).  Requires N,E < 2^21.

// ---------------- counting-sort-by-dst preprocessing ----------------

__global__ void k_hist(const int* __restrict__ dst, int* __restrict__ cnt, int E) {
    int e = blockIdx.x * 256 + threadIdx.x;
    if (e < E) atomicAdd(&cnt[dst[e]], 1);
}

// inclusive scan of 1024-chunk -> offsets[1+g]; chunk totals -> blksum; zeroes cnt for reuse as cursor
__global__ void k_scan1(int* __restrict__ cnt, int* __restrict__ offsets,
                        int* __restrict__ blksum, int N) {
    __shared__ int sh[1024];
    int tid = threadIdx.x;
    int g = blockIdx.x * 1024 + tid;
    sh[tid] = (g < N) ? cnt[g] : 0;
    if (g < N) cnt[g] = 0;   // cursor reset folded in
    __syncthreads();
#pragma unroll
    for (int off = 1; off < 1024; off <<= 1) {
        int t = (tid >= off) ? sh[tid - off] : 0;
        __syncthreads();
        sh[tid] += t;
        __syncthreads();
    }
    if (g < N) offsets[1 + g] = sh[tid];
    if (tid == 1023) blksum[blockIdx.x] = sh[tid];
}

__global__ void k_scan2(int* __restrict__ blksum, int nb) {
    __shared__ int sh[256];
    int tid = threadIdx.x;
    int orig = (tid < nb) ? blksum[tid] : 0;
    sh[tid] = orig;
    __syncthreads();
#pragma unroll
    for (int off = 1; off < 256; off <<= 1) {
        int t = (tid >= off) ? sh[tid - off] : 0;
        __syncthreads();
        sh[tid] += t;
        __syncthreads();
    }
    if (tid < nb) blksum[tid] = sh[tid] - orig;  // exclusive
}

__global__ void k_scan3(int* __restrict__ offsets, const int* __restrict__ blksum, int N) {
    int g = blockIdx.x * 1024 + threadIdx.x;
    if (g < N) offsets[1 + g] += blksum[blockIdx.x];
    if (g == 0) offsets[0] = 0;
}

// ---------------- fill: one 8B scattered store per edge, (d,s,e) packed ----------------
__global__ void k_fill(const int* __restrict__ dst, const int* __restrict__ src,
                       const int* __restrict__ offsets, int* __restrict__ cursor,
                       unsigned long long* __restrict__ pack, int E) {
    int e = blockIdx.x * 256 + threadIdx.x;
    if (e >= E) return;
    int d = dst[e];
    int s = src[e];
    int p = atomicAdd(&cursor[d], 1);
    int pos = offsets[d] + p;
    pack[pos] = ((unsigned long long)d << 42) | ((unsigned long long)s << 21) | (unsigned long long)e;
}

// ---------------- fused edge encoder + in-LDS segment reduction ----------------
__global__ __launch_bounds__(256) void k_edge_reduce(
    const float* __restrict__ efeat, const float* __restrict__ nfeat,
    const unsigned long long* __restrict__ pack,
    const float* __restrict__ We, const float* __restrict__ be,
    float* __restrict__ hn0sum, int E)
{
    __shared__ float lmsg[256][25];   // pad 25: stride coprime with 32 banks
    __shared__ int ld[256];
    __shared__ unsigned long long hm[4];
    __shared__ int dnb[2];            // d of global predecessor / successor
    int tid = threadIdx.x;
    int B0 = blockIdx.x * 256;
    int i = B0 + tid;
    int nvalid = min(256, E - B0);
    if (tid == 0) {
        dnb[0] = (B0 > 0) ? (int)(pack[B0 - 1] >> 42) : -9;
        dnb[1] = (B0 + 256 < E) ? (int)(pack[B0 + 256] >> 42) : -9;
    }
    int d = -3, s = 0;
    float ef[EDGE_F];
    if (i < E) {
        unsigned long long v = pack[i];
        int e = (int)(v & 0x1FFFFF);
        s = (int)((v >> 21) & 0x1FFFFF);
        d = (int)(v >> 42);
        const float4* ef4 = (const float4*)(efeat + (size_t)e * EDGE_F);
#pragma unroll
        for (int q = 0; q < EDGE_F / 4; ++q) {
            float4 t = ef4[q];
            ef[4 * q + 0] = t.x; ef[4 * q + 1] = t.y; ef[4 * q + 2] = t.z; ef[4 * q + 3] = t.w;
        }
    }
    ld[tid] = d;
    __syncthreads();

    bool head = (i < E) && (tid == 0 || d != ld[tid - 1]);
    unsigned long long m = __ballot(head);
    int wv = tid >> 6, lane = tid & 63;
    if (lane == 0) hm[wv] = m;
    __syncthreads();

#pragma unroll
    for (int c = 0; c < 2; ++c) {
        if (i < E) {
            float acc[24];
#pragma unroll
            for (int j = 0; j < 24; ++j) acc[j] = be[c * 24 + j];     // wave-uniform -> s_load
#pragma unroll
            for (int k = 0; k < EDGE_F; ++k) {
                float ek = ef[k];
#pragma unroll
                for (int j = 0; j < 24; ++j)
                    acc[j] = fmaf(ek, We[k * IN_F + c * 24 + j], acc[j]);
            }
            const float4* n4 = (const float4*)(nfeat + (size_t)s * IN_F + c * 24);
#pragma unroll
            for (int q = 0; q < 6; ++q) {
                float4 nv = n4[q];
                lmsg[tid][4 * q + 0] = fmaxf(acc[4 * q + 0], 0.0f) * nv.x;
                lmsg[tid][4 * q + 1] = fmaxf(acc[4 * q + 1], 0.0f) * nv.y;
                lmsg[tid][4 * q + 2] = fmaxf(acc[4 * q + 2], 0.0f) * nv.z;
                lmsg[tid][4 * q + 3] = fmaxf(acc[4 * q + 3], 0.0f) * nv.w;
            }
        }
        __syncthreads();

        int dprev = dnb[0], dnext = dnb[1];
        unsigned long long mym = hm[wv];
        while (mym) {
            int rel = __ffsll(mym) - 1;
            mym &= mym - 1;
            int a = wv * 64 + rel;
            // find next head strictly after a
            int b = nvalid;
            {
                unsigned long long mm = (rel < 63) ? (hm[wv] & (~0ULL << (rel + 1))) : 0ULL;
                int w2 = wv;
                while (true) {
                    if (mm) { b = w2 * 64 + __ffsll(mm) - 1; break; }
                    if (++w2 >= 4) break;
                    mm = hm[w2];
                }
            }
            int dd = ld[a];
            bool cut = (a == 0 && dd == dprev) || (b == nvalid && dd == dnext);
            if (lane < 24) {
                float sum = 0.0f;
                int t = a;
                for (; t + 2 <= b; t += 2) sum += lmsg[t][lane] + lmsg[t + 1][lane];
                if (t < b) sum += lmsg[t][lane];
                float* dp = hn0sum + (size_t)dd * IN_F + c * 24 + lane;
                if (cut) atomicAdd(dp, sum);
                else *dp = sum;
            }
        }
        __syncthreads();   // lmsg reused by next chunk
    }
}

// ---------------- hcat builder: hcat = [nfeat, hn0sum/deg] ----------------
__global__ void k_hcatb(const float* __restrict__ nfeat, const float* __restrict__ hn0sum,
                        const int* __restrict__ offsets, float* __restrict__ hcat, int N) {
    int idx = blockIdx.x * 256 + threadIdx.x;
    int total = N * 12;
    if (idx >= total) return;
    int node = idx / 12;
    int q = idx - node * 12;
    float4 nv = ((const float4*)nfeat)[idx];
    float4 hv = ((const float4*)hn0sum)[idx];
    int deg = offsets[node + 1] - offsets[node];
    float ivn = 1.0f / (float)max(deg, 1);
    float4* out4 = (float4*)(hcat + (size_t)node * 96);
    out4[q] = nv;
    float4 o;
    o.x = hv.x * ivn; o.y = hv.y * ivn; o.z = hv.z * ivn; o.w = hv.w * ivn;
    out4[12 + q] = o;
}

// ---------------- mm1p (fused layer-2 gather, scalarized addressing,
// 16-deep batches, clamped final batch -> NO serial scalar tail).
// Indices u>=rem in the last batch are clamped to sx[0] (always valid; the
// <=120B pack over-read lands in the adjacent in-workspace region) and
// excluded from the sum via fmaf with a 0/1 scalar gate.
__global__ __launch_bounds__(256) void k_mm1p(
    const float* __restrict__ hcat,
    const unsigned long long* __restrict__ pack, const int* __restrict__ offsets,
    const float* __restrict__ W1s, const float* __restrict__ W1n,
    const float* __restrict__ b1, const float* __restrict__ W2n,
    float* __restrict__ h1, float* __restrict__ y2, int N) {
    __shared__ float xs[16][192];
    __shared__ float hs[16][128];
    int wv = threadIdx.x >> 6, lane = threadIdx.x & 63;
    int base = blockIdx.x * 16;
#pragma unroll
    for (int rr = 0; rr < 4; ++rr) {
        int row = base + wv * 4 + rr;
        int r_u = __builtin_amdgcn_readfirstlane(row < N ? row : N - 1);  // wave-uniform
        // self features (uniform base + lane offset)
        xs[wv * 4 + rr][lane] = hcat[(size_t)r_u * 96 + lane];
        if (lane < 32) xs[wv * 4 + rr][64 + lane] = hcat[(size_t)r_u * 96 + 64 + lane];
        // neighbor mean
        int s0 = offsets[r_u], s1 = offsets[r_u + 1];
        float ivn = 1.0f / (float)max(s1 - s0, 1);
        float sA = 0.0f, sB = 0.0f;
        int i = s0;
        // full 16-batches, unpredicated
        for (; i + 16 <= s1; i += 16) {
            int iu = __builtin_amdgcn_readfirstlane(i);
            int sx[16];
#pragma unroll
            for (int u = 0; u < 16; ++u)
                sx[u] = (int)((pack[(size_t)iu + u] >> 21) & 0x1FFFFF);   // uniform -> SALU
            float av[16];
#pragma unroll
            for (int u = 0; u < 16; ++u)
                av[u] = hcat[(size_t)sx[u] * 96 + lane];                  // SGPR base gather
            if (lane < 32) {
                float bv[16];
#pragma unroll
                for (int u = 0; u < 16; ++u)
                    bv[u] = hcat[(size_t)sx[u] * 96 + 64 + lane];
                float b01 = (bv[0] + bv[1]) + (bv[2] + bv[3]);
                float b23 = (bv[4] + bv[5]) + (bv[6] + bv[7]);
                float b45 = (bv[8] + bv[9]) + (bv[10] + bv[11]);
                float b67 = (bv[12] + bv[13]) + (bv[14] + bv[15]);
                sB += (b01 + b23) + (b45 + b67);
            }
            float a01 = (av[0] + av[1]) + (av[2] + av[3]);
            float a23 = (av[4] + av[5]) + (av[6] + av[7]);
            float a45 = (av[8] + av[9]) + (av[10] + av[11]);
            float a67 = (av[12] + av[13]) + (av[14] + av[15]);
            sA += (a01 + a23) + (a45 + a67);
        }
        // clamped final batch (rem in [1,15]): no serial tail
        if (i < s1) {
            int iu  = __builtin_amdgcn_readfirstlane(i);
            int rem = __builtin_amdgcn_readfirstlane(s1 - i);     // uniform, 1..15
            int sx[16];
#pragma unroll
            for (int u = 0; u < 16; ++u) {
                int t = (int)((pack[(size_t)iu + u] >> 21) & 0x1FFFFF);
                sx[u] = (u < rem) ? t : sx[0];                    // clamp to valid row
            }
            float av[16];
#pragma unroll
            for (int u = 0; u < 16; ++u)
                av[u] = hcat[(size_t)sx[u] * 96 + lane];
            if (lane < 32) {
                float bv[16];
#pragma unroll
                for (int u = 0; u < 16; ++u)
                    bv[u] = hcat[(size_t)sx[u] * 96 + 64 + lane];
#pragma unroll
                for (int u = 0; u < 16; ++u) {
                    float g = (u < rem) ? 1.0f : 0.0f;
                    sB = fmaf(g, bv[u], sB);
                }
            }
#pragma unroll
            for (int u = 0; u < 16; ++u) {
                float g = (u < rem) ? 1.0f : 0.0f;
                sA = fmaf(g, av[u], sA);
            }
        }
        xs[wv * 4 + rr][96 + lane] = sA * ivn;
        if (lane < 32) xs[wv * 4 + rr][160 + lane] = sB * ivn;
    }
    __syncthreads();
    const float* x0 = xs[wv * 4 + 0];
    const float* x1 = xs[wv * 4 + 1];
    const float* x2 = xs[wv * 4 + 2];
    const float* x3 = xs[wv * 4 + 3];
    int c0 = lane, c1 = lane + 64;
    float a00 = b1[c0], a01 = b1[c1];
    float a10 = a00, a11 = a01, a20 = a00, a21 = a01, a30 = a00, a31 = a01;
#pragma unroll 4
    for (int k = 0; k < 96; ++k) {
        float w0 = W1s[k * 128 + c0], w1 = W1s[k * 128 + c1];
        a00 = fmaf(x0[k], w0, a00); a01 = fmaf(x0[k], w1, a01);
        a10 = fmaf(x1[k], w0, a10); a11 = fmaf(x1[k], w1, a11);
        a20 = fmaf(x2[k], w0, a20); a21 = fmaf(x2[k], w1, a21);
        a30 = fmaf(x3[k], w0, a30); a31 = fmaf(x3[k], w1, a31);
    }
#pragma unroll 4
    for (int k = 0; k < 96; ++k) {
        float w0 = W1n[k * 128 + c0], w1 = W1n[k * 128 + c1];
        a00 = fmaf(x0[96 + k], w0, a00); a01 = fmaf(x0[96 + k], w1, a01);
        a10 = fmaf(x1[96 + k], w0, a10); a11 = fmaf(x1[96 + k], w1, a11);
        a20 = fmaf(x2[96 + k], w0, a20); a21 = fmaf(x2[96 + k], w1, a21);
        a30 = fmaf(x3[96 + k], w0, a30); a31 = fmaf(x3[96 + k], w1, a31);
    }
    float accs[4][2] = {{a00, a01}, {a10, a11}, {a20, a21}, {a30, a31}};
#pragma unroll
    for (int rr = 0; rr < 4; ++rr) {
        int row = base + wv * 4 + rr;
        float v0 = fmaxf(accs[rr][0], 0.0f);
        float v1 = fmaxf(accs[rr][1], 0.0f);
        hs[wv * 4 + rr][c0] = v0;      // same-wave LDS write/read: no barrier needed
        hs[wv * 4 + rr][c1] = v1;
        if (row < N) {
            h1[(size_t)row * 128 + c0] = v0;
            h1[(size_t)row * 128 + c1] = v1;
        }
    }
    // projection: y2 = h1 @ W2n (128 -> 64), rows stay in LDS
    const float* p0 = hs[wv * 4 + 0];
    const float* p1 = hs[wv * 4 + 1];
    const float* p2 = hs[wv * 4 + 2];
    const float* p3 = hs[wv * 4 + 3];
    float q0 = 0.0f, q1 = 0.0f, q2 = 0.0f, q3 = 0.0f;
#pragma unroll 4
    for (int k = 0; k < 128; ++k) {
        float w = W2n[k * 64 + lane];
        q0 = fmaf(p0[k], w, q0); q1 = fmaf(p1[k], w, q1);
        q2 = fmaf(p2[k], w, q2); q3 = fmaf(p3[k], w, q3);
    }
    float qs[4] = {q0, q1, q2, q3};
#pragma unroll
    for (int rr = 0; rr < 4; ++rr) {
        int row = base + wv * 4 + rr;
        if (row < N) y2[(size_t)row * 64 + lane] = qs[rr];
    }
}

// ---------------- mm2b (fused layer-3 gather, 16-deep + clamped tail):
// out = h1@W2s + b2 + mean(y2[src]) ----------------
__global__ __launch_bounds__(256) void k_mm2b(
    const float* __restrict__ h1, const float* __restrict__ y2,
    const unsigned long long* __restrict__ pack, const int* __restrict__ offsets,
    const float* __restrict__ W2s, const float* __restrict__ b2,
    float* __restrict__ out, int N) {
    __shared__ float xs[16][128];
    int wv = threadIdx.x >> 6, lane = threadIdx.x & 63;
    int base = blockIdx.x * 16;
    float gs[4];
#pragma unroll
    for (int rr = 0; rr < 4; ++rr) {
        int row = base + wv * 4 + rr;
        int r_u = __builtin_amdgcn_readfirstlane(row < N ? row : N - 1);  // wave-uniform
        xs[wv * 4 + rr][lane]      = h1[(size_t)r_u * 128 + lane];
        xs[wv * 4 + rr][lane + 64] = h1[(size_t)r_u * 128 + lane + 64];
        int s0 = offsets[r_u], s1 = offsets[r_u + 1];
        float ivn = 1.0f / (float)max(s1 - s0, 1);
        float sum = 0.0f;
        int i = s0;
        for (; i + 16 <= s1; i += 16) {
            int iu = __builtin_amdgcn_readfirstlane(i);
            int sx[16];
#pragma unroll
            for (int u = 0; u < 16; ++u)
                sx[u] = (int)((pack[(size_t)iu + u] >> 21) & 0x1FFFFF);   // uniform -> SALU
            float av[16];
#pragma unroll
            for (int u = 0; u < 16; ++u)
                av[u] = y2[(size_t)sx[u] * 64 + lane];                    // SGPR base gather
            float a01 = (av[0] + av[1]) + (av[2] + av[3]);
            float a23 = (av[4] + av[5]) + (av[6] + av[7]);
            float a45 = (av[8] + av[9]) + (av[10] + av[11]);
            float a67 = (av[12] + av[13]) + (av[14] + av[15]);
            sum += (a01 + a23) + (a45 + a67);
        }
        if (i < s1) {
            int iu  = __builtin_amdgcn_readfirstlane(i);
            int rem = __builtin_amdgcn_readfirstlane(s1 - i);     // uniform, 1..15
            int sx[16];
#pragma unroll
            for (int u = 0; u < 16; ++u) {
                int t = (int)((pack[(size_t)iu + u] >> 21) & 0x1FFFFF);
                sx[u] = (u < rem) ? t : sx[0];
            }
            float av[16];
#pragma unroll
            for (int u = 0; u < 16; ++u)
                av[u] = y2[(size_t)sx[u] * 64 + lane];
#pragma unroll
            for (int u = 0; u < 16; ++u) {
                float g = (u < rem) ? 1.0f : 0.0f;
                sum = fmaf(g, av[u], sum);
            }
        }
        gs[rr] = sum * ivn;
    }
    __syncthreads();
    const float* x0 = xs[wv * 4 + 0];
    const float* x1 = xs[wv * 4 + 1];
    const float* x2 = xs[wv * 4 + 2];
    const float* x3 = xs[wv * 4 + 3];
    float a0 = b2[lane], a1 = a0, a2 = a0, a3 = a0;
#pragma unroll 4
    for (int k = 0; k < 128; ++k) {
        float w = W2s[k * 64 + lane];
        a0 = fmaf(x0[k], w, a0); a1 = fmaf(x1[k], w, a1);
        a2 = fmaf(x2[k], w, a2); a3 = fmaf(x3[k], w, a3);
    }
    float accs[4] = {a0, a1, a2, a3};
#pragma unroll
    for (int rr = 0; rr < 4; ++rr) {
        int row = base + wv * 4 + rr;
        if (row < N) out[(size_t)row * 64 + lane] = accs[rr] + gs[rr];
    }
}

extern "C" void kernel_launch(void* const* d_in, const int* in_sizes, int n_in,
                              void* d_out, int out_size, void* d_ws, size_t ws_size,
                              hipStream_t stream) {
    const float* nfeat = (const float*)d_in[0];
    const float* efeat = (const float*)d_in[1];
    const int*   src   = (const int*)d_in[2];
    const int*   dst   = (const int*)d_in[3];
    const float* We    = (const float*)d_in[4];
    const float* be    = (const float*)d_in[5];
    const float* W1s   = (const float*)d_in[6];
    const float* W1n   = (const float*)d_in[7];
    const float* b1    = (const float*)d_in[8];
    const float* W2s   = (const float*)d_in[9];
    const float* W2n   = (const float*)d_in[10];
    const float* b2    = (const float*)d_in[11];
    float* out = (float*)d_out;

    int N = in_sizes[0] / IN_F;
    int E = in_sizes[2];

    // workspace layout (4B words):
    // cursor[N] | hn0sum[48N] | offsets[N+64] | blksum[256] | pack[2E] |
    // hcat[96N] | h1[128N] | y2[64N]
    // single memset covers cursor+hn0sum (contiguous 49N)
    int*                cursor  = (int*)d_ws;
    float*              hn0sum  = (float*)(cursor + N);
    int*                offsets = (int*)(hn0sum + (size_t)48 * N);
    int*                blksum  = offsets + N + 64;
    unsigned long long* pack    = (unsigned long long*)(blksum + 256);  // N even -> 8B aligned
    float*              hcat    = (float*)(pack + E);
    float*              h1      = hcat + (size_t)96 * N;
    float*              y2      = h1 + (size_t)128 * N;

    int nb = (N + 1023) / 1024;  // 98 for N=100000 (<=256 required by k_scan2)

    (void)hipMemsetAsync(cursor, 0, (size_t)49 * N * sizeof(float), stream);
    k_hist<<<(E + 255) / 256, 256, 0, stream>>>(dst, cursor, E);
    k_scan1<<<nb, 1024, 0, stream>>>(cursor, offsets, blksum, N);   // also re-zeros cursor
    k_scan2<<<1, 256, 0, stream>>>(blksum, nb);
    k_scan3<<<nb, 1024, 0, stream>>>(offsets, blksum, N);

    k_fill<<<(E + 255) / 256, 256, 0, stream>>>(dst, src, offsets, cursor, pack, E);
    k_edge_reduce<<<(E + 255) / 256, 256, 0, stream>>>(efeat, nfeat, pack, We, be, hn0sum, E);
    k_hcatb<<<(N * 12 + 255) / 256, 256, 0, stream>>>(nfeat, hn0sum, offsets, hcat, N);
    k_mm1p<<<(N + 15) / 16, 256, 0, stream>>>(hcat, pack, offsets, W1s, W1n, b1, W2n, h1, y2, N);
    k_mm2b<<<(N + 15) / 16, 256, 0, stream>>>(h1, y2, pack, offsets, W2s, b2, out, N);
}

// Round 8
// 851.701 us; speedup vs baseline: 1.0410x; 1.0410x over previous
//
#include <hip/hip_runtime.h>

#define IN_F 48
#define EDGE_F 32
#define HID_F 128
#define OUT_F 64

// pack layout: e in bits [0,21), s in [21,42), d in [42,63).  Requires N,E < 2^21.

// ---------------- counting-sort-by-dst preprocessing ----------------

__global__ void k_hist(const int* __restrict__ dst, int* __restrict__ cnt, int E) {
    int e = blockIdx.x * 256 + threadIdx.x;
    if (e < E) atomicAdd(&cnt[dst[e]], 1);
}

// inclusive scan of 1024-chunk -> offsets[1+g]; chunk totals -> blksum; zeroes cnt for reuse as cursor
__global__ void k_scan1(int* __restrict__ cnt, int* __restrict__ offsets,
                        int* __restrict__ blksum, int N) {
    __shared__ int sh[1024];
    int tid = threadIdx.x;
    int g = blockIdx.x * 1024 + tid;
    sh[tid] = (g < N) ? cnt[g] : 0;
    if (g < N) cnt[g] = 0;   // cursor reset folded in
    __syncthreads();
#pragma unroll
    for (int off = 1; off < 1024; off <<= 1) {
        int t = (tid >= off) ? sh[tid - off] : 0;
        __syncthreads();
        sh[tid] += t;
        __syncthreads();
    }
    if (g < N) offsets[1 + g] = sh[tid];
    if (tid == 1023) blksum[blockIdx.x] = sh[tid];
}

__global__ void k_scan2(int* __restrict__ blksum, int nb) {
    __shared__ int sh[256];
    int tid = threadIdx.x;
    int orig = (tid < nb) ? blksum[tid] : 0;
    sh[tid] = orig;
    __syncthreads();
#pragma unroll
    for (int off = 1; off < 256; off <<= 1) {
        int t = (tid >= off) ? sh[tid - off] : 0;
        __syncthreads();
        sh[tid] += t;
        __syncthreads();
    }
    if (tid < nb) blksum[tid] = sh[tid] - orig;  // exclusive
}

__global__ void k_scan3(int* __restrict__ offsets, const int* __restrict__ blksum, int N) {
    int g = blockIdx.x * 1024 + threadIdx.x;
    if (g < N) offsets[1 + g] += blksum[blockIdx.x];
    if (g == 0) offsets[0] = 0;
}

// ---------------- fill: one 8B scattered store per edge, (d,s,e) packed ----------------
__global__ void k_fill(const int* __restrict__ dst, const int* __restrict__ src,
                       const int* __restrict__ offsets, int* __restrict__ cursor,
                       unsigned long long* __restrict__ pack, int E) {
    int e = blockIdx.x * 256 + threadIdx.x;
    if (e >= E) return;
    int d = dst[e];
    int s = src[e];
    int p = atomicAdd(&cursor[d], 1);
    int pos = offsets[d] + p;
    pack[pos] = ((unsigned long long)d << 42) | ((unsigned long long)s << 21) | (unsigned long long)e;
}

// ---------------- fused edge encoder + in-LDS segment reduction ----------------
__global__ __launch_bounds__(256) void k_edge_reduce(
    const float* __restrict__ efeat, const float* __restrict__ nfeat,
    const unsigned long long* __restrict__ pack,
    const float* __restrict__ We, const float* __restrict__ be,
    float* __restrict__ hn0sum, int E)
{
    __shared__ float lmsg[256][25];   // pad 25: stride coprime with 32 banks
    __shared__ int ld[256];
    __shared__ unsigned long long hm[4];
    __shared__ int dnb[2];            // d of global predecessor / successor
    int tid = threadIdx.x;
    int B0 = blockIdx.x * 256;
    int i = B0 + tid;
    int nvalid = min(256, E - B0);
    if (tid == 0) {
        dnb[0] = (B0 > 0) ? (int)(pack[B0 - 1] >> 42) : -9;
        dnb[1] = (B0 + 256 < E) ? (int)(pack[B0 + 256] >> 42) : -9;
    }
    int d = -3, s = 0;
    float ef[EDGE_F];
    if (i < E) {
        unsigned long long v = pack[i];
        int e = (int)(v & 0x1FFFFF);
        s = (int)((v >> 21) & 0x1FFFFF);
        d = (int)(v >> 42);
        const float4* ef4 = (const float4*)(efeat + (size_t)e * EDGE_F);
#pragma unroll
        for (int q = 0; q < EDGE_F / 4; ++q) {
            float4 t = ef4[q];
            ef[4 * q + 0] = t.x; ef[4 * q + 1] = t.y; ef[4 * q + 2] = t.z; ef[4 * q + 3] = t.w;
        }
    }
    ld[tid] = d;
    __syncthreads();

    bool head = (i < E) && (tid == 0 || d != ld[tid - 1]);
    unsigned long long m = __ballot(head);
    int wv = tid >> 6, lane = tid & 63;
    if (lane == 0) hm[wv] = m;
    __syncthreads();

#pragma unroll
    for (int c = 0; c < 2; ++c) {
        if (i < E) {
            float acc[24];
#pragma unroll
            for (int j = 0; j < 24; ++j) acc[j] = be[c * 24 + j];     // wave-uniform -> s_load
#pragma unroll
            for (int k = 0; k < EDGE_F; ++k) {
                float ek = ef[k];
#pragma unroll
                for (int j = 0; j < 24; ++j)
                    acc[j] = fmaf(ek, We[k * IN_F + c * 24 + j], acc[j]);
            }
            const float4* n4 = (const float4*)(nfeat + (size_t)s * IN_F + c * 24);
#pragma unroll
            for (int q = 0; q < 6; ++q) {
                float4 nv = n4[q];
                lmsg[tid][4 * q + 0] = fmaxf(acc[4 * q + 0], 0.0f) * nv.x;
                lmsg[tid][4 * q + 1] = fmaxf(acc[4 * q + 1], 0.0f) * nv.y;
                lmsg[tid][4 * q + 2] = fmaxf(acc[4 * q + 2], 0.0f) * nv.z;
                lmsg[tid][4 * q + 3] = fmaxf(acc[4 * q + 3], 0.0f) * nv.w;
            }
        }
        __syncthreads();

        int dprev = dnb[0], dnext = dnb[1];
        unsigned long long mym = hm[wv];
        while (mym) {
            int rel = __ffsll(mym) - 1;
            mym &= mym - 1;
            int a = wv * 64 + rel;
            // find next head strictly after a
            int b = nvalid;
            {
                unsigned long long mm = (rel < 63) ? (hm[wv] & (~0ULL << (rel + 1))) : 0ULL;
                int w2 = wv;
                while (true) {
                    if (mm) { b = w2 * 64 + __ffsll(mm) - 1; break; }
                    if (++w2 >= 4) break;
                    mm = hm[w2];
                }
            }
            int dd = ld[a];
            bool cut = (a == 0 && dd == dprev) || (b == nvalid && dd == dnext);
            if (lane < 24) {
                float sum = 0.0f;
                int t = a;
                for (; t + 2 <= b; t += 2) sum += lmsg[t][lane] + lmsg[t + 1][lane];
                if (t < b) sum += lmsg[t][lane];
                float* dp = hn0sum + (size_t)dd * IN_F + c * 24 + lane;
                if (cut) atomicAdd(dp, sum);
                else *dp = sum;
            }
        }
        __syncthreads();   // lmsg reused by next chunk
    }
}

// ---------------- hcat builder: hcat = [nfeat, hn0sum/deg] ----------------
__global__ void k_hcatb(const float* __restrict__ nfeat, const float* __restrict__ hn0sum,
                        const int* __restrict__ offsets, float* __restrict__ hcat, int N) {
    int idx = blockIdx.x * 256 + threadIdx.x;
    int total = N * 12;
    if (idx >= total) return;
    int node = idx / 12;
    int q = idx - node * 12;
    float4 nv = ((const float4*)nfeat)[idx];
    float4 hv = ((const float4*)hn0sum)[idx];
    int deg = offsets[node + 1] - offsets[node];
    float ivn = 1.0f / (float)max(deg, 1);
    float4* out4 = (float4*)(hcat + (size_t)node * 96);
    out4[q] = nv;
    float4 o;
    o.x = hv.x * ivn; o.y = hv.y * ivn; o.z = hv.z * ivn; o.w = hv.w * ivn;
    out4[12 + q] = o;
}

// ---------------- mm1p (fused layer-2 gather, scalarized addressing, 8-deep
// batches = r5 form).  NO inter-wave barrier: xs/hs rows wv*4..wv*4+3 are
// written and read ONLY by wave wv, so waves flow gather->matmul
// independently and one wave's matmul VALU hides another's gather latency.
__global__ __launch_bounds__(256) void k_mm1p(
    const float* __restrict__ hcat,
    const unsigned long long* __restrict__ pack, const int* __restrict__ offsets,
    const float* __restrict__ W1s, const float* __restrict__ W1n,
    const float* __restrict__ b1, const float* __restrict__ W2n,
    float* __restrict__ h1, float* __restrict__ y2, int N) {
    __shared__ float xs[16][192];
    __shared__ float hs[16][128];
    int wv = threadIdx.x >> 6, lane = threadIdx.x & 63;
    int base = blockIdx.x * 16;
#pragma unroll
    for (int rr = 0; rr < 4; ++rr) {
        int row = base + wv * 4 + rr;
        int r_u = __builtin_amdgcn_readfirstlane(row < N ? row : N - 1);  // wave-uniform
        // self features (uniform base + lane offset)
        xs[wv * 4 + rr][lane] = hcat[(size_t)r_u * 96 + lane];
        if (lane < 32) xs[wv * 4 + rr][64 + lane] = hcat[(size_t)r_u * 96 + 64 + lane];
        // neighbor mean
        int s0 = offsets[r_u], s1 = offsets[r_u + 1];
        float ivn = 1.0f / (float)max(s1 - s0, 1);
        float sA = 0.0f, sB = 0.0f;
        int i = s0;
        for (; i + 8 <= s1; i += 8) {
            int iu = __builtin_amdgcn_readfirstlane(i);
            int sx[8];
#pragma unroll
            for (int u = 0; u < 8; ++u)
                sx[u] = (int)((pack[(size_t)iu + u] >> 21) & 0x1FFFFF);   // uniform -> SALU
            float av[8];
#pragma unroll
            for (int u = 0; u < 8; ++u)
                av[u] = hcat[(size_t)sx[u] * 96 + lane];                  // SGPR base gather
            sA += ((av[0] + av[1]) + (av[2] + av[3])) + ((av[4] + av[5]) + (av[6] + av[7]));
            if (lane < 32) {        // half-wave B loads, uniform base (single exec toggle)
                float bv[8];
#pragma unroll
                for (int u = 0; u < 8; ++u)
                    bv[u] = hcat[(size_t)sx[u] * 96 + 64 + lane];
                sB += ((bv[0] + bv[1]) + (bv[2] + bv[3])) + ((bv[4] + bv[5]) + (bv[6] + bv[7]));
            }
        }
        for (; i < s1; ++i) {
            int iu = __builtin_amdgcn_readfirstlane(i);
            int sxt = (int)((pack[iu] >> 21) & 0x1FFFFF);
            sA += hcat[(size_t)sxt * 96 + lane];
            if (lane < 32) sB += hcat[(size_t)sxt * 96 + 64 + lane];
        }
        xs[wv * 4 + rr][96 + lane] = sA * ivn;
        if (lane < 32) xs[wv * 4 + rr][160 + lane] = sB * ivn;
    }
    // no __syncthreads(): xs rows are wave-private (written & read by same wave)
    const float* x0 = xs[wv * 4 + 0];
    const float* x1 = xs[wv * 4 + 1];
    const float* x2 = xs[wv * 4 + 2];
    const float* x3 = xs[wv * 4 + 3];
    int c0 = lane, c1 = lane + 64;
    float a00 = b1[c0], a01 = b1[c1];
    float a10 = a00, a11 = a01, a20 = a00, a21 = a01, a30 = a00, a31 = a01;
#pragma unroll 4
    for (int k = 0; k < 96; ++k) {
        float w0 = W1s[k * 128 + c0], w1 = W1s[k * 128 + c1];
        a00 = fmaf(x0[k], w0, a00); a01 = fmaf(x0[k], w1, a01);
        a10 = fmaf(x1[k], w0, a10); a11 = fmaf(x1[k], w1, a11);
        a20 = fmaf(x2[k], w0, a20); a21 = fmaf(x2[k], w1, a21);
        a30 = fmaf(x3[k], w0, a30); a31 = fmaf(x3[k], w1, a31);
    }
#pragma unroll 4
    for (int k = 0; k < 96; ++k) {
        float w0 = W1n[k * 128 + c0], w1 = W1n[k * 128 + c1];
        a00 = fmaf(x0[96 + k], w0, a00); a01 = fmaf(x0[96 + k], w1, a01);
        a10 = fmaf(x1[96 + k], w0, a10); a11 = fmaf(x1[96 + k], w1, a11);
        a20 = fmaf(x2[96 + k], w0, a20); a21 = fmaf(x2[96 + k], w1, a21);
        a30 = fmaf(x3[96 + k], w0, a30); a31 = fmaf(x3[96 + k], w1, a31);
    }
    float accs[4][2] = {{a00, a01}, {a10, a11}, {a20, a21}, {a30, a31}};
#pragma unroll
    for (int rr = 0; rr < 4; ++rr) {
        int row = base + wv * 4 + rr;
        float v0 = fmaxf(accs[rr][0], 0.0f);
        float v1 = fmaxf(accs[rr][1], 0.0f);
        hs[wv * 4 + rr][c0] = v0;      // same-wave LDS write/read: no barrier needed
        hs[wv * 4 + rr][c1] = v1;
        if (row < N) {
            h1[(size_t)row * 128 + c0] = v0;
            h1[(size_t)row * 128 + c1] = v1;
        }
    }
    // projection: y2 = h1 @ W2n (128 -> 64), rows stay in LDS
    const float* p0 = hs[wv * 4 + 0];
    const float* p1 = hs[wv * 4 + 1];
    const float* p2 = hs[wv * 4 + 2];
    const float* p3 = hs[wv * 4 + 3];
    float q0 = 0.0f, q1 = 0.0f, q2 = 0.0f, q3 = 0.0f;
#pragma unroll 4
    for (int k = 0; k < 128; ++k) {
        float w = W2n[k * 64 + lane];
        q0 = fmaf(p0[k], w, q0); q1 = fmaf(p1[k], w, q1);
        q2 = fmaf(p2[k], w, q2); q3 = fmaf(p3[k], w, q3);
    }
    float qs[4] = {q0, q1, q2, q3};
#pragma unroll
    for (int rr = 0; rr < 4; ++rr) {
        int row = base + wv * 4 + rr;
        if (row < N) y2[(size_t)row * 64 + lane] = qs[rr];
    }
}

// ---------------- mm2b (fused layer-3 gather, scalarized, 8-deep = r5 form):
// out = h1@W2s + b2 + mean(y2[src]); no inter-wave barrier (xs wave-private).
__global__ __launch_bounds__(256) void k_mm2b(
    const float* __restrict__ h1, const float* __restrict__ y2,
    const unsigned long long* __restrict__ pack, const int* __restrict__ offsets,
    const float* __restrict__ W2s, const float* __restrict__ b2,
    float* __restrict__ out, int N) {
    __shared__ float xs[16][128];
    int wv = threadIdx.x >> 6, lane = threadIdx.x & 63;
    int base = blockIdx.x * 16;
    float gs[4];
#pragma unroll
    for (int rr = 0; rr < 4; ++rr) {
        int row = base + wv * 4 + rr;
        int r_u = __builtin_amdgcn_readfirstlane(row < N ? row : N - 1);  // wave-uniform
        xs[wv * 4 + rr][lane]      = h1[(size_t)r_u * 128 + lane];
        xs[wv * 4 + rr][lane + 64] = h1[(size_t)r_u * 128 + lane + 64];
        int s0 = offsets[r_u], s1 = offsets[r_u + 1];
        float ivn = 1.0f / (float)max(s1 - s0, 1);
        float sum = 0.0f;
        int i = s0;
        for (; i + 8 <= s1; i += 8) {
            int iu = __builtin_amdgcn_readfirstlane(i);
            int sx[8];
#pragma unroll
            for (int u = 0; u < 8; ++u)
                sx[u] = (int)((pack[(size_t)iu + u] >> 21) & 0x1FFFFF);   // uniform -> SALU
            float av[8];
#pragma unroll
            for (int u = 0; u < 8; ++u)
                av[u] = y2[(size_t)sx[u] * 64 + lane];                    // SGPR base gather
            sum += ((av[0] + av[1]) + (av[2] + av[3])) + ((av[4] + av[5]) + (av[6] + av[7]));
        }
        for (; i < s1; ++i) {
            int iu = __builtin_amdgcn_readfirstlane(i);
            int sxt = (int)((pack[iu] >> 21) & 0x1FFFFF);
            sum += y2[(size_t)sxt * 64 + lane];
        }
        gs[rr] = sum * ivn;
    }
    // no __syncthreads(): xs rows are wave-private
    const float* x0 = xs[wv * 4 + 0];
    const float* x1 = xs[wv * 4 + 1];
    const float* x2 = xs[wv * 4 + 2];
    const float* x3 = xs[wv * 4 + 3];
    float a0 = b2[lane], a1 = a0, a2 = a0, a3 = a0;
#pragma unroll 4
    for (int k = 0; k < 128; ++k) {
        float w = W2s[k * 64 + lane];
        a0 = fmaf(x0[k], w, a0); a1 = fmaf(x1[k], w, a1);
        a2 = fmaf(x2[k], w, a2); a3 = fmaf(x3[k], w, a3);
    }
    float accs[4] = {a0, a1, a2, a3};
#pragma unroll
    for (int rr = 0; rr < 4; ++rr) {
        int row = base + wv * 4 + rr;
        if (row < N) out[(size_t)row * 64 + lane] = accs[rr] + gs[rr];
    }
}

extern "C" void kernel_launch(void* const* d_in, const int* in_sizes, int n_in,
                              void* d_out, int out_size, void* d_ws, size_t ws_size,
                              hipStream_t stream) {
    const float* nfeat = (const float*)d_in[0];
    const float* efeat = (const float*)d_in[1];
    const int*   src   = (const int*)d_in[2];
    const int*   dst   = (const int*)d_in[3];
    const float* We    = (const float*)d_in[4];
    const float* be    = (const float*)d_in[5];
    const float* W1s   = (const float*)d_in[6];
    const float* W1n   = (const float*)d_in[7];
    const float* b1    = (const float*)d_in[8];
    const float* W2s   = (const float*)d_in[9];
    const float* W2n   = (const float*)d_in[10];
    const float* b2    = (const float*)d_in[11];
    float* out = (float*)d_out;

    int N = in_sizes[0] / IN_F;
    int E = in_sizes[2];

    // workspace layout (4B words):
    // cursor[N] | hn0sum[48N] | offsets[N+64] | blksum[256] | pack[2E] |
    // hcat[96N] | h1[128N] | y2[64N]
    // single memset covers cursor+hn0sum (contiguous 49N)
    int*                cursor  = (int*)d_ws;
    float*              hn0sum  = (float*)(cursor + N);
    int*                offsets = (int*)(hn0sum + (size_t)48 * N);
    int*                blksum  = offsets + N + 64;
    unsigned long long* pack    = (unsigned long long*)(blksum + 256);  // N even -> 8B aligned
    float*              hcat    = (float*)(pack + E);
    float*              h1      = hcat + (size_t)96 * N;
    float*              y2      = h1 + (size_t)128 * N;

    int nb = (N + 1023) / 1024;  // 98 for N=100000 (<=256 required by k_scan2)

    (void)hipMemsetAsync(cursor, 0, (size_t)49 * N * sizeof(float), stream);
    k_hist<<<(E + 255) / 256, 256, 0, stream>>>(dst, cursor, E);
    k_scan1<<<nb, 1024, 0, stream>>>(cursor, offsets, blksum, N);   // also re-zeros cursor
    k_scan2<<<1, 256, 0, stream>>>(blksum, nb);
    k_scan3<<<nb, 1024, 0, stream>>>(offsets, blksum, N);

    k_fill<<<(E + 255) / 256, 256, 0, stream>>>(dst, src, offsets, cursor, pack, E);
    k_edge_reduce<<<(E + 255) / 256, 256, 0, stream>>>(efeat, nfeat, pack, We, be, hn0sum, E);
    k_hcatb<<<(N * 12 + 255) / 256, 256, 0, stream>>>(nfeat, hn0sum, offsets, hcat, N);
    k_mm1p<<<(N + 15) / 16, 256, 0, stream>>>(hcat, pack, offsets, W1s, W1n, b1, W2n, h1, y2, N);
    k_mm2b<<<(N + 15) / 16, 256, 0, stream>>>(h1, y2, pack, offsets, W2s, b2, out, N);
}